// Round 6
// baseline (164.890 us; speedup 1.0000x reference)
//
#include <hip/hip_runtime.h>
#include <stdint.h>

// ProbSparse attention (Informer): B=4, L=2048, H=8, D=64, factor=5 -> U_part=u=40.
// out = broadcast mean(V) except top-40 rows per (b,h) get softmax(Q K^T/8) V.
// Row selection is bit-exact jax.random.randint(key(42),(2048,40),0,2048)
// under jax_threefry_partitionable=True (verified passing).
//
// R4: XCD-affinity remap (fetch 73->16.4 MB). R5: quarter-wave dots (k_M 175->47 us,
// cross-lane-pipe model confirmed). R6: 8-lane sample groups (26 cross-lane ops/wave,
// ~L2-gather floor), fuse vmean, fuse fill+scatter via bitmap (8->6 kernels).

static constexpr int Bc = 4, Lc = 2048, Hc = 8, Dc = 64, NUc = 40;
static constexpr int NCH = 8, CHK = 256;  // key chunks for attention

struct TF2 { uint32_t a, b; };

__host__ __device__ constexpr uint32_t rotl32c(uint32_t x, int r) {
    return (x << r) | (x >> (32 - r));
}

// Threefry-2x32, 20 rounds (jax._src.prng.threefry2x32), constexpr-foldable.
__host__ __device__ constexpr TF2 tf2x32c(uint32_t k0, uint32_t k1, uint32_t x0, uint32_t x1) {
    uint32_t ks[3] = {k0, k1, k0 ^ k1 ^ 0x1BD11BDAu};
    const int R0[4] = {13, 15, 26, 6};
    const int R1[4] = {17, 29, 16, 24};
    x0 += ks[0];
    x1 += ks[1];
    for (int i = 0; i < 5; ++i) {
        const int* R = (i & 1) ? R1 : R0;
        for (int j = 0; j < 4; ++j) {
            x0 += x1;
            x1 = rotl32c(x1, R[j]);
            x1 ^= x0;
        }
        x0 += ks[(i + 1) % 3];
        x1 += ks[(i + 2) % 3] + (uint32_t)(i + 1);
    }
    return TF2{x0, x1};
}

// ---------------- k_M: sampled sparsity measure --------------------------------
// wave per q-row. 8-lane groups each own one sample/iter: lane gl holds dims
// [8gl..8gl+7] (2x float4); reduce = 3 stages over 8 lanes; 8 samples/iter,
// 5 iters; 3-stage cross-group combine. 26 cross-lane ops/wave total.
// XCD-affinity remap keeps each (b,h) K-panel resident in one XCD's L2.
__global__ __launch_bounds__(256) void k_M(const float* __restrict__ Q,
                                           const float* __restrict__ K,
                                           float* __restrict__ M) {
    constexpr TF2 K2 = tf2x32c(0u, 42u, 0u, 1u);  // second key of split(key(42))
    int lane = threadIdx.x & 63;
    int w = threadIdx.x >> 6;
    int blk = blockIdx.x;            // 16384 blocks
    int xcd = blk & 7;
    int local = blk >> 3;            // 0..2047 within XCD
    int bh = xcd * 4 + (local >> 9); // 4 panels per XCD
    int q = (local & 511) * 4 + w;
    int b = bh >> 3, h = bh & 7;
    // lane s (<40) computes index_sample[q][s]
    TF2 r = tf2x32c(K2.a, K2.b, 0u, (uint32_t)(q * 40 + lane));
    int myidx = (int)((r.a ^ r.b) & 2047u);

    int grp = lane >> 3;  // 0..7 : sample group
    int gl = lane & 7;    // 0..7 : dim fragment (8 floats)
    const float4* Qrow =
        reinterpret_cast<const float4*>(Q + (((size_t)(b * Lc + q)) * Hc + h) * Dc);
    float4 qv0 = Qrow[2 * gl];
    float4 qv1 = Qrow[2 * gl + 1];
    const float* Kbh = K + ((size_t)b * Lc * Hc + h) * Dc;  // + l*512

    float mx = -INFINITY, sm = 0.f;
#pragma unroll
    for (int i = 0; i < 5; ++i) {
        int kk = __shfl(myidx, i * 8 + grp, 64);  // per-group sample index
        const float4* Kr = reinterpret_cast<const float4*>(Kbh + (size_t)kk * 512 + 8 * gl);
        float4 kv0 = Kr[0];
        float4 kv1 = Kr[1];
        float pv = qv0.x * kv0.x + qv0.y * kv0.y + qv0.z * kv0.z + qv0.w * kv0.w +
                   qv1.x * kv1.x + qv1.y * kv1.y + qv1.z * kv1.z + qv1.w * kv1.w;
#pragma unroll
        for (int m = 1; m < 8; m <<= 1) pv += __shfl_xor(pv, m, 64);
        mx = fmaxf(mx, pv);
        sm += pv;
    }
    // combine the 8 groups (each has stats over its 5 samples)
#pragma unroll
    for (int m = 8; m < 64; m <<= 1) {
        mx = fmaxf(mx, __shfl_xor(mx, m, 64));
        sm += __shfl_xor(sm, m, 64);
    }
    if (lane == 0) M[bh * Lc + q] = mx - sm * (1.0f / 2048.0f);
}

// ---------------- k_topk: register-resident iterative argmax (ties -> smaller idx) --
// Also emits a 2048-bit membership bitmap per (b,h) for the fused output kernel.
__global__ __launch_bounds__(256) void k_topk(const float* __restrict__ M, int* __restrict__ top,
                                              uint32_t* __restrict__ gmask) {
    __shared__ float wvs[4];
    __shared__ int wis[4];
    __shared__ int sel[NUc];
    int bh = blockIdx.x;
    int t = threadIdx.x, lane = t & 63, w = t >> 6;
    float v[8];
#pragma unroll
    for (int i = 0; i < 8; ++i) v[i] = M[bh * Lc + i * 256 + t];
    float bv;
    int bi;
    auto recompute = [&]() {
        bv = v[0];
        bi = t;
#pragma unroll
        for (int i = 1; i < 8; ++i)
            if (v[i] > bv) { bv = v[i]; bi = i * 256 + t; }
    };
    recompute();
    for (int it = 0; it < NUc; ++it) {
        float cv = bv;
        int ci = bi;
#pragma unroll
        for (int m = 1; m < 64; m <<= 1) {
            float ov = __shfl_xor(cv, m, 64);
            int oi = __shfl_xor(ci, m, 64);
            if (ov > cv || (ov == cv && oi < ci)) { cv = ov; ci = oi; }
        }
        if (lane == 0) { wvs[w] = cv; wis[w] = ci; }
        __syncthreads();
        float gv = wvs[0];
        int gi = wis[0];
#pragma unroll
        for (int ww = 1; ww < 4; ++ww) {
            float ov = wvs[ww];
            int oi = wis[ww];
            if (ov > gv || (ov == gv && oi < gi)) { gv = ov; gi = oi; }
        }
        if (t == 0) {
            top[bh * NUc + it] = gi;
            sel[it] = gi;
        }
        if ((gi & 255) == t) {  // owner removes and rescans its 8
            v[gi >> 8] = -INFINITY;
            recompute();
        }
        __syncthreads();
    }
    if (t < 64) {
        uint32_t word = 0;
#pragma unroll
        for (int j = 0; j < NUc; ++j) {
            int s = sel[j];
            if ((s >> 5) == t) word |= 1u << (s & 31);
        }
        gmask[bh * 64 + t] = word;
    }
}

// ---------------- V mean (fused partial+reduce): one block per (b,h) -------------
__global__ __launch_bounds__(256) void k_vmean(const float* __restrict__ V,
                                               float* __restrict__ vm) {
    __shared__ float4 r[256];
    int bh = blockIdx.x;
    int b = bh >> 3, h = bh & 7;
    int t = threadIdx.x, dq = t & 15, c = t >> 4;  // c in 0..15
    const float4* V4 = reinterpret_cast<const float4*>(V);
    float4 s = make_float4(0.f, 0.f, 0.f, 0.f);
    for (int l = c; l < Lc; l += 16) {
        float4 p = V4[(size_t)((b * Lc + l) * Hc + h) * 16 + dq];
        s.x += p.x; s.y += p.y; s.z += p.z; s.w += p.w;
    }
    r[t] = s;
    __syncthreads();
    if (t < 16) {
        float4 a = r[t];
#pragma unroll
        for (int g = 1; g < 16; ++g) {
            float4 p = r[t + 16 * g];
            a.x += p.x; a.y += p.y; a.z += p.z; a.w += p.w;
        }
        a.x *= (1.0f / 2048.0f); a.y *= (1.0f / 2048.0f);
        a.z *= (1.0f / 2048.0f); a.w *= (1.0f / 2048.0f);
        reinterpret_cast<float4*>(vm)[bh * 16 + t] = a;
    }
}

// ---------------- attention partials: block = (b,h,chunk of 256 keys) ------------
__global__ __launch_bounds__(256) void k_attn_part(const float* __restrict__ Q,
                                                   const float* __restrict__ K,
                                                   const float* __restrict__ V,
                                                   const int* __restrict__ top,
                                                   float* __restrict__ wsO,
                                                   float* __restrict__ wsm,
                                                   float* __restrict__ wsl) {
    __shared__ float Qs[40][64];        // 10 KB
    __shared__ float pT[4][64][44];     // 44 KB (wave, key-local, u + pad)
    __shared__ float mw[4][40], lw[4][40];
    __shared__ float Mgs[40], Lgs[40];
    __shared__ int tqs[40];
    int blk = blockIdx.x;  // bh*NCH + chunk
    int chunk = blk & (NCH - 1), bh = blk >> 3;
    int b = bh >> 3, h = bh & 7;
    int t = threadIdx.x, w = t >> 6, lane = t & 63;

    if (t < 40) tqs[t] = top[bh * NUc + t];
    __syncthreads();
    for (int i = t; i < 40 * 64; i += 256) {
        int u = i >> 6, d = i & 63;
        Qs[u][d] = Q[(((size_t)(b * Lc + tqs[u])) * Hc + h) * Dc + d];
    }
    __syncthreads();

    // scores: thread t owns key kg = chunk*256 + t; acc[u] = dot(Q[u], K[kg])
    int kg = chunk * CHK + t;
    const float4* Kr = reinterpret_cast<const float4*>(&K[(((size_t)(b * Lc + kg)) * Hc + h) * Dc]);
    float acc[40];
#pragma unroll
    for (int u = 0; u < 40; ++u) acc[u] = 0.f;
#pragma unroll
    for (int i = 0; i < 16; ++i) {
        float4 kv = Kr[i];
#pragma unroll
        for (int u = 0; u < 40; ++u) {
            float4 qv = *reinterpret_cast<const float4*>(&Qs[u][i * 4]);
            acc[u] += qv.x * kv.x + qv.y * kv.y + qv.z * kv.z + qv.w * kv.w;
        }
    }
    // transpose into wave-local LDS (scaled); same-wave, no barrier needed
#pragma unroll
    for (int u = 0; u < 40; ++u) pT[w][lane][u] = acc[u] * 0.125f;
    // wave-local softmax stats over this wave's 64 keys (lane u < 40)
    if (lane < 40) {
        float m = -INFINITY;
        for (int k = 0; k < 64; ++k) m = fmaxf(m, pT[w][k][lane]);
        float s = 0.f;
        for (int k = 0; k < 64; ++k) {
            float e = __expf(pT[w][k][lane] - m);
            pT[w][k][lane] = e;
            s += e;
        }
        mw[w][lane] = m;
        lw[w][lane] = s;
    }
    // PV over this wave's 64 keys: lane = d, acc[u] = sum_k p[u][k] * V[k][d]
#pragma unroll
    for (int u = 0; u < 40; ++u) acc[u] = 0.f;
    const float* Vbh = V + ((size_t)b * Lc * Hc + h) * Dc;
    for (int k = 0; k < 64; ++k) {
        int kk = chunk * CHK + w * 64 + k;
        float vv = Vbh[(size_t)kk * 512 + lane];
#pragma unroll
        for (int u0 = 0; u0 < 40; u0 += 4) {
            float4 p4 = *reinterpret_cast<const float4*>(&pT[w][k][u0]);
            acc[u0] += p4.x * vv;
            acc[u0 + 1] += p4.y * vv;
            acc[u0 + 2] += p4.z * vv;
            acc[u0 + 3] += p4.w * vv;
        }
    }
    __syncthreads();
    // combine 4 waves' stats -> chunk stats; lw becomes per-wave rescale factor
    if (t < 40) {
        float m = fmaxf(fmaxf(mw[0][t], mw[1][t]), fmaxf(mw[2][t], mw[3][t]));
        float L = 0.f;
#pragma unroll
        for (int ww = 0; ww < 4; ++ww) {
            float f = __expf(mw[ww][t] - m);
            L += lw[ww][t] * f;
            lw[ww][t] = f;
        }
        Mgs[t] = m;
        Lgs[t] = L;
    }
    __syncthreads();
    // scale own O by factor, stage into pT region (p no longer needed)
    float* Ow = &pT[w][0][0];
#pragma unroll
    for (int u = 0; u < 40; ++u) Ow[u * 64 + lane] = acc[u] * lw[w][u];
    __syncthreads();
    // sum across waves -> chunk partial (unnormalized, referenced to chunk max)
    const float* o0 = &pT[0][0][0];
    const float* o1 = &pT[1][0][0];
    const float* o2 = &pT[2][0][0];
    const float* o3 = &pT[3][0][0];
    for (int i = t; i < 40 * 64; i += 256)
        wsO[(size_t)blk * 2560 + i] = o0[i] + o1[i] + o2[i] + o3[i];
    if (t < 40) {
        wsm[blk * 40 + t] = Mgs[t];
        wsl[blk * 40 + t] = Lgs[t];
    }
}

// ---------------- combine 8 chunk-partials -> staged rows ------------------------
__global__ __launch_bounds__(256) void k_attn_comb(const float* __restrict__ wsO,
                                                   const float* __restrict__ wsm,
                                                   const float* __restrict__ wsl,
                                                   float* __restrict__ stage) {
    __shared__ float cm[8][40], cl[8][40], cf[8][40];
    int bh = blockIdx.x;
    int t = threadIdx.x;
    // 320 pairs, 256 threads -> strided loop (R2 bug was `if (t < 320)`).
    for (int i = t; i < 8 * 40; i += 256) {
        int c = i / 40, u = i % 40;
        cm[c][u] = wsm[(bh * 8 + c) * 40 + u];
        cl[c][u] = wsl[(bh * 8 + c) * 40 + u];
    }
    __syncthreads();
    if (t < 40) {
        float m = -INFINITY;
#pragma unroll
        for (int c = 0; c < 8; ++c) m = fmaxf(m, cm[c][t]);
        float L = 0.f;
#pragma unroll
        for (int c = 0; c < 8; ++c) {
            float f = __expf(cm[c][t] - m);
            L += cl[c][t] * f;
            cf[c][t] = f;
        }
        float inv = 1.0f / L;
#pragma unroll
        for (int c = 0; c < 8; ++c) cf[c][t] *= inv;
    }
    __syncthreads();
    for (int i = t; i < 2560; i += 256) {
        int u = i >> 6;
        float val = 0.f;
#pragma unroll
        for (int c = 0; c < 8; ++c) val += wsO[((size_t)(bh * 8 + c)) * 2560 + i] * cf[c][u];
        stage[(size_t)bh * 2560 + i] = val;
    }
}

// ---------------- fused output: vmean fill + attended-row scatter ----------------
// Each output float4 written exactly once; bitmap decides source.
__global__ void k_out(const float* __restrict__ stage, const float* __restrict__ vm,
                      const int* __restrict__ top, const uint32_t* __restrict__ gmask,
                      float* __restrict__ out) {
    int o4 = blockIdx.x * blockDim.x + threadIdx.x;  // over 1M float4
    if (o4 >= Bc * Lc * Hc * (Dc / 4)) return;
    int dq = o4 & 15;
    int h = (o4 >> 4) & 7;
    int bl = o4 >> 7;  // b*2048 + l
    int b = bl >> 11, l = bl & 2047;
    int bh = b * 8 + h;
    float4 v;
    uint32_t wmask = gmask[bh * 64 + (l >> 5)];
    if ((wmask >> (l & 31)) & 1u) {
        int u = 0;
#pragma unroll
        for (int j = 0; j < NUc; ++j)
            if (top[bh * NUc + j] == l) u = j;
        v = reinterpret_cast<const float4*>(stage)[(bh * NUc + u) * 16 + dq];
    } else {
        v = reinterpret_cast<const float4*>(vm)[bh * 16 + dq];
    }
    reinterpret_cast<float4*>(out)[o4] = v;
}

extern "C" void kernel_launch(void* const* d_in, const int* in_sizes, int n_in,
                              void* d_out, int out_size, void* d_ws, size_t ws_size,
                              hipStream_t stream) {
    (void)in_sizes; (void)n_in; (void)out_size; (void)ws_size;
    const float* Q = (const float*)d_in[0];
    const float* K = (const float*)d_in[1];
    const float* V = (const float*)d_in[2];
    float* out = (float*)d_out;

    // d_out-as-scratch (16 MB; all consumed before k_out overwrites it):
    float* wsO = (float*)d_out;                           // 0 .. 2.62 MB
    float* wsm = (float*)((char*)d_out + 3145728);        // 40 KB
    float* wsl = (float*)((char*)d_out + 3276800);        // 40 KB
    float* M   = (float*)((char*)d_out + 4194304);        // 256 KB
    // d_ws (read by k_out): ~352 KB total
    int*      top   = (int*)d_ws;                         // 6.4 KB (pad to 8K)
    float*    stage = (float*)((char*)d_ws + 8192);       // 320 KB
    float*    vm    = (float*)((char*)d_ws + 335872);     // 8 KB
    uint32_t* gmask = (uint32_t*)((char*)d_ws + 344064);  // 8 KB

    hipLaunchKernelGGL(k_M, dim3(Bc * Hc * Lc / 4), dim3(256), 0, stream, Q, K, M);
    hipLaunchKernelGGL(k_topk, dim3(Bc * Hc), dim3(256), 0, stream, M, top, gmask);
    hipLaunchKernelGGL(k_vmean, dim3(Bc * Hc), dim3(256), 0, stream, V, vm);
    hipLaunchKernelGGL(k_attn_part, dim3(Bc * Hc * NCH), dim3(256), 0, stream, Q, K, V, top,
                       wsO, wsm, wsl);
    hipLaunchKernelGGL(k_attn_comb, dim3(Bc * Hc), dim3(256), 0, stream, wsO, wsm, wsl, stage);
    hipLaunchKernelGGL(k_out, dim3(4096), dim3(256), 0, stream, stage, vm, top, gmask, out);
}

// Round 7
// 122.684 us; speedup vs baseline: 1.3440x; 1.3440x over previous
//
#include <hip/hip_runtime.h>
#include <stdint.h>

// ProbSparse attention (Informer): B=4, L=2048, H=8, D=64, factor=5 -> U_part=u=40.
// out = broadcast mean(V) except top-40 rows per (b,h) get softmax(Q K^T/8) V.
// Row selection is bit-exact jax.random.randint(key(42),(2048,40),0,2048)
// under jax_threefry_partitionable=True (verified passing).
//
// R4: XCD remap (fetch 73->16.4 MB). R5: quarter-wave dots (k_M 175->47 us).
// R6: 8-lane groups (k_M ~<30 us) BUT vmean fusion to 32 blocks = 66 us latency
// disaster (occupancy 1.3%). R7: delete vmean; V column-sums fall out of
// k_attn_part's PV loop (V read once, ever); k_attn_comb finishes vm. 5 kernels.

static constexpr int Bc = 4, Lc = 2048, Hc = 8, Dc = 64, NUc = 40;
static constexpr int NCH = 8, CHK = 256;  // key chunks for attention

struct TF2 { uint32_t a, b; };

__host__ __device__ constexpr uint32_t rotl32c(uint32_t x, int r) {
    return (x << r) | (x >> (32 - r));
}

// Threefry-2x32, 20 rounds (jax._src.prng.threefry2x32), constexpr-foldable.
__host__ __device__ constexpr TF2 tf2x32c(uint32_t k0, uint32_t k1, uint32_t x0, uint32_t x1) {
    uint32_t ks[3] = {k0, k1, k0 ^ k1 ^ 0x1BD11BDAu};
    const int R0[4] = {13, 15, 26, 6};
    const int R1[4] = {17, 29, 16, 24};
    x0 += ks[0];
    x1 += ks[1];
    for (int i = 0; i < 5; ++i) {
        const int* R = (i & 1) ? R1 : R0;
        for (int j = 0; j < 4; ++j) {
            x0 += x1;
            x1 = rotl32c(x1, R[j]);
            x1 ^= x0;
        }
        x0 += ks[(i + 1) % 3];
        x1 += ks[(i + 2) % 3] + (uint32_t)(i + 1);
    }
    return TF2{x0, x1};
}

// ---------------- k_M: sampled sparsity measure --------------------------------
// wave per q-row. 8-lane groups each own one sample/iter: lane gl holds dims
// [8gl..8gl+7] (2x float4); reduce = 3 stages over 8 lanes; 8 samples/iter,
// 5 iters; 3-stage cross-group combine. 26 cross-lane ops/wave total.
// XCD-affinity remap keeps each (b,h) K-panel resident in one XCD's L2.
__global__ __launch_bounds__(256) void k_M(const float* __restrict__ Q,
                                           const float* __restrict__ K,
                                           float* __restrict__ M) {
    constexpr TF2 K2 = tf2x32c(0u, 42u, 0u, 1u);  // second key of split(key(42))
    int lane = threadIdx.x & 63;
    int w = threadIdx.x >> 6;
    int blk = blockIdx.x;            // 16384 blocks
    int xcd = blk & 7;
    int local = blk >> 3;            // 0..2047 within XCD
    int bh = xcd * 4 + (local >> 9); // 4 panels per XCD
    int q = (local & 511) * 4 + w;
    int b = bh >> 3, h = bh & 7;
    // lane s (<40) computes index_sample[q][s]
    TF2 r = tf2x32c(K2.a, K2.b, 0u, (uint32_t)(q * 40 + lane));
    int myidx = (int)((r.a ^ r.b) & 2047u);

    int grp = lane >> 3;  // 0..7 : sample group
    int gl = lane & 7;    // 0..7 : dim fragment (8 floats)
    const float4* Qrow =
        reinterpret_cast<const float4*>(Q + (((size_t)(b * Lc + q)) * Hc + h) * Dc);
    float4 qv0 = Qrow[2 * gl];
    float4 qv1 = Qrow[2 * gl + 1];
    const float* Kbh = K + ((size_t)b * Lc * Hc + h) * Dc;  // + l*512

    float mx = -INFINITY, sm = 0.f;
#pragma unroll
    for (int i = 0; i < 5; ++i) {
        int kk = __shfl(myidx, i * 8 + grp, 64);  // per-group sample index
        const float4* Kr = reinterpret_cast<const float4*>(Kbh + (size_t)kk * 512 + 8 * gl);
        float4 kv0 = Kr[0];
        float4 kv1 = Kr[1];
        float pv = qv0.x * kv0.x + qv0.y * kv0.y + qv0.z * kv0.z + qv0.w * kv0.w +
                   qv1.x * kv1.x + qv1.y * kv1.y + qv1.z * kv1.z + qv1.w * kv1.w;
#pragma unroll
        for (int m = 1; m < 8; m <<= 1) pv += __shfl_xor(pv, m, 64);
        mx = fmaxf(mx, pv);
        sm += pv;
    }
    // combine the 8 groups (each has stats over its 5 samples)
#pragma unroll
    for (int m = 8; m < 64; m <<= 1) {
        mx = fmaxf(mx, __shfl_xor(mx, m, 64));
        sm += __shfl_xor(sm, m, 64);
    }
    if (lane == 0) M[bh * Lc + q] = mx - sm * (1.0f / 2048.0f);
}

// ---------------- k_topk: register-resident iterative argmax (ties -> smaller idx) --
// Also emits a 2048-bit membership bitmap per (b,h) for the fused output kernel.
__global__ __launch_bounds__(256) void k_topk(const float* __restrict__ M, int* __restrict__ top,
                                              uint32_t* __restrict__ gmask) {
    __shared__ float wvs[4];
    __shared__ int wis[4];
    __shared__ int sel[NUc];
    int bh = blockIdx.x;
    int t = threadIdx.x, lane = t & 63, w = t >> 6;
    float v[8];
#pragma unroll
    for (int i = 0; i < 8; ++i) v[i] = M[bh * Lc + i * 256 + t];
    float bv;
    int bi;
    auto recompute = [&]() {
        bv = v[0];
        bi = t;
#pragma unroll
        for (int i = 1; i < 8; ++i)
            if (v[i] > bv) { bv = v[i]; bi = i * 256 + t; }
    };
    recompute();
    for (int it = 0; it < NUc; ++it) {
        float cv = bv;
        int ci = bi;
#pragma unroll
        for (int m = 1; m < 64; m <<= 1) {
            float ov = __shfl_xor(cv, m, 64);
            int oi = __shfl_xor(ci, m, 64);
            if (ov > cv || (ov == cv && oi < ci)) { cv = ov; ci = oi; }
        }
        if (lane == 0) { wvs[w] = cv; wis[w] = ci; }
        __syncthreads();
        float gv = wvs[0];
        int gi = wis[0];
#pragma unroll
        for (int ww = 1; ww < 4; ++ww) {
            float ov = wvs[ww];
            int oi = wis[ww];
            if (ov > gv || (ov == gv && oi < gi)) { gv = ov; gi = oi; }
        }
        if (t == 0) {
            top[bh * NUc + it] = gi;
            sel[it] = gi;
        }
        if ((gi & 255) == t) {  // owner removes and rescans its 8
            v[gi >> 8] = -INFINITY;
            recompute();
        }
        __syncthreads();
    }
    if (t < 64) {
        uint32_t word = 0;
#pragma unroll
        for (int j = 0; j < NUc; ++j) {
            int s = sel[j];
            if ((s >> 5) == t) word |= 1u << (s & 31);
        }
        gmask[bh * 64 + t] = word;
    }
}

// ---------------- attention partials: block = (b,h,chunk of 256 keys) ------------
// Also emits per-chunk V column-sums (vpart) from the PV loop's V stream.
__global__ __launch_bounds__(256) void k_attn_part(const float* __restrict__ Q,
                                                   const float* __restrict__ K,
                                                   const float* __restrict__ V,
                                                   const int* __restrict__ top,
                                                   float* __restrict__ wsO,
                                                   float* __restrict__ wsm,
                                                   float* __restrict__ wsl,
                                                   float* __restrict__ vpart) {
    __shared__ float Qs[40][64];        // 10 KB
    __shared__ float pT[4][64][44];     // 44 KB (wave, key-local, u + pad)
    __shared__ float mw[4][40], lw[4][40];
    __shared__ float Mgs[40], Lgs[40];
    __shared__ float vsum[4][64];       // 1 KB: per-wave V column partial sums
    __shared__ int tqs[40];
    int blk = blockIdx.x;  // bh*NCH + chunk
    int chunk = blk & (NCH - 1), bh = blk >> 3;
    int b = bh >> 3, h = bh & 7;
    int t = threadIdx.x, w = t >> 6, lane = t & 63;

    if (t < 40) tqs[t] = top[bh * NUc + t];
    __syncthreads();
    for (int i = t; i < 40 * 64; i += 256) {
        int u = i >> 6, d = i & 63;
        Qs[u][d] = Q[(((size_t)(b * Lc + tqs[u])) * Hc + h) * Dc + d];
    }
    __syncthreads();

    // scores: thread t owns key kg = chunk*256 + t; acc[u] = dot(Q[u], K[kg])
    int kg = chunk * CHK + t;
    const float4* Kr = reinterpret_cast<const float4*>(&K[(((size_t)(b * Lc + kg)) * Hc + h) * Dc]);
    float acc[40];
#pragma unroll
    for (int u = 0; u < 40; ++u) acc[u] = 0.f;
#pragma unroll
    for (int i = 0; i < 16; ++i) {
        float4 kv = Kr[i];
#pragma unroll
        for (int u = 0; u < 40; ++u) {
            float4 qv = *reinterpret_cast<const float4*>(&Qs[u][i * 4]);
            acc[u] += qv.x * kv.x + qv.y * kv.y + qv.z * kv.z + qv.w * kv.w;
        }
    }
    // transpose into wave-local LDS (scaled); same-wave, no barrier needed
#pragma unroll
    for (int u = 0; u < 40; ++u) pT[w][lane][u] = acc[u] * 0.125f;
    // wave-local softmax stats over this wave's 64 keys (lane u < 40)
    if (lane < 40) {
        float m = -INFINITY;
        for (int k = 0; k < 64; ++k) m = fmaxf(m, pT[w][k][lane]);
        float s = 0.f;
        for (int k = 0; k < 64; ++k) {
            float e = __expf(pT[w][k][lane] - m);
            pT[w][k][lane] = e;
            s += e;
        }
        mw[w][lane] = m;
        lw[w][lane] = s;
    }
    // PV over this wave's 64 keys: lane = d, acc[u] = sum_k p[u][k] * V[k][d].
    // Free byproduct: vs = sum_k V[k][d] (for the V-mean output).
#pragma unroll
    for (int u = 0; u < 40; ++u) acc[u] = 0.f;
    float vs = 0.f;
    const float* Vbh = V + ((size_t)b * Lc * Hc + h) * Dc;
    for (int k = 0; k < 64; ++k) {
        int kk = chunk * CHK + w * 64 + k;
        float vv = Vbh[(size_t)kk * 512 + lane];
        vs += vv;
#pragma unroll
        for (int u0 = 0; u0 < 40; u0 += 4) {
            float4 p4 = *reinterpret_cast<const float4*>(&pT[w][k][u0]);
            acc[u0] += p4.x * vv;
            acc[u0 + 1] += p4.y * vv;
            acc[u0 + 2] += p4.z * vv;
            acc[u0 + 3] += p4.w * vv;
        }
    }
    vsum[w][lane] = vs;
    __syncthreads();
    // combine 4 waves' stats -> chunk stats; lw becomes per-wave rescale factor
    if (t < 40) {
        float m = fmaxf(fmaxf(mw[0][t], mw[1][t]), fmaxf(mw[2][t], mw[3][t]));
        float L = 0.f;
#pragma unroll
        for (int ww = 0; ww < 4; ++ww) {
            float f = __expf(mw[ww][t] - m);
            L += lw[ww][t] * f;
            lw[ww][t] = f;
        }
        Mgs[t] = m;
        Lgs[t] = L;
    }
    if (t >= 64 && t < 128) {  // wave 1 lanes: chunk V column sums
        int d = t - 64;
        vpart[blk * 64 + d] = vsum[0][d] + vsum[1][d] + vsum[2][d] + vsum[3][d];
    }
    __syncthreads();
    // scale own O by factor, stage into pT region (p no longer needed)
    float* Ow = &pT[w][0][0];
#pragma unroll
    for (int u = 0; u < 40; ++u) Ow[u * 64 + lane] = acc[u] * lw[w][u];
    __syncthreads();
    // sum across waves -> chunk partial (unnormalized, referenced to chunk max)
    const float* o0 = &pT[0][0][0];
    const float* o1 = &pT[1][0][0];
    const float* o2 = &pT[2][0][0];
    const float* o3 = &pT[3][0][0];
    for (int i = t; i < 40 * 64; i += 256)
        wsO[(size_t)blk * 2560 + i] = o0[i] + o1[i] + o2[i] + o3[i];
    if (t < 40) {
        wsm[blk * 40 + t] = Mgs[t];
        wsl[blk * 40 + t] = Lgs[t];
    }
}

// ---------------- combine 8 chunk-partials -> staged rows + finish V-mean --------
__global__ __launch_bounds__(256) void k_attn_comb(const float* __restrict__ wsO,
                                                   const float* __restrict__ wsm,
                                                   const float* __restrict__ wsl,
                                                   const float* __restrict__ vpart,
                                                   float* __restrict__ stage,
                                                   float* __restrict__ vm) {
    __shared__ float cm[8][40], cl[8][40], cf[8][40];
    int bh = blockIdx.x;
    int t = threadIdx.x;
    // 320 pairs, 256 threads -> strided loop (R2 bug was `if (t < 320)`).
    for (int i = t; i < 8 * 40; i += 256) {
        int c = i / 40, u = i % 40;
        cm[c][u] = wsm[(bh * 8 + c) * 40 + u];
        cl[c][u] = wsl[(bh * 8 + c) * 40 + u];
    }
    __syncthreads();
    if (t < 40) {
        float m = -INFINITY;
#pragma unroll
        for (int c = 0; c < 8; ++c) m = fmaxf(m, cm[c][t]);
        float L = 0.f;
#pragma unroll
        for (int c = 0; c < 8; ++c) {
            float f = __expf(cm[c][t] - m);
            L += cl[c][t] * f;
            cf[c][t] = f;
        }
        float inv = 1.0f / L;
#pragma unroll
        for (int c = 0; c < 8; ++c) cf[c][t] *= inv;
    }
    if (t >= 64 && t < 128) {  // finish V-mean: reduce 8 chunk partials
        int d = t - 64;
        float s = 0.f;
#pragma unroll
        for (int c = 0; c < 8; ++c) s += vpart[(bh * 8 + c) * 64 + d];
        vm[bh * 64 + d] = s * (1.0f / 2048.0f);
    }
    __syncthreads();
    for (int i = t; i < 2560; i += 256) {
        int u = i >> 6;
        float val = 0.f;
#pragma unroll
        for (int c = 0; c < 8; ++c) val += wsO[((size_t)(bh * 8 + c)) * 2560 + i] * cf[c][u];
        stage[(size_t)bh * 2560 + i] = val;
    }
}

// ---------------- fused output: vmean fill + attended-row scatter ----------------
// Each output float4 written exactly once; bitmap decides source.
__global__ void k_out(const float* __restrict__ stage, const float* __restrict__ vm,
                      const int* __restrict__ top, const uint32_t* __restrict__ gmask,
                      float* __restrict__ out) {
    int o4 = blockIdx.x * blockDim.x + threadIdx.x;  // over 1M float4
    if (o4 >= Bc * Lc * Hc * (Dc / 4)) return;
    int dq = o4 & 15;
    int h = (o4 >> 4) & 7;
    int bl = o4 >> 7;  // b*2048 + l
    int b = bl >> 11, l = bl & 2047;
    int bh = b * 8 + h;
    float4 v;
    uint32_t wmask = gmask[bh * 64 + (l >> 5)];
    if ((wmask >> (l & 31)) & 1u) {
        int u = 0;
#pragma unroll
        for (int j = 0; j < NUc; ++j)
            if (top[bh * NUc + j] == l) u = j;
        v = reinterpret_cast<const float4*>(stage)[(bh * NUc + u) * 16 + dq];
    } else {
        v = reinterpret_cast<const float4*>(vm)[bh * 16 + dq];
    }
    reinterpret_cast<float4*>(out)[o4] = v;
}

extern "C" void kernel_launch(void* const* d_in, const int* in_sizes, int n_in,
                              void* d_out, int out_size, void* d_ws, size_t ws_size,
                              hipStream_t stream) {
    (void)in_sizes; (void)n_in; (void)out_size; (void)ws_size;
    const float* Q = (const float*)d_in[0];
    const float* K = (const float*)d_in[1];
    const float* V = (const float*)d_in[2];
    float* out = (float*)d_out;

    // d_out-as-scratch (16 MB; all consumed before k_out overwrites it):
    float* wsO   = (float*)d_out;                         // 0 .. 2.62 MB
    float* wsm   = (float*)((char*)d_out + 3145728);      // 40 KB
    float* wsl   = (float*)((char*)d_out + 3276800);      // 40 KB
    float* vpart = (float*)((char*)d_out + 3407872);      // 64 KB
    float* M     = (float*)((char*)d_out + 4194304);      // 256 KB
    // d_ws (read by k_out): ~352 KB total
    int*      top   = (int*)d_ws;                         // 6.4 KB (pad to 8K)
    float*    stage = (float*)((char*)d_ws + 8192);       // 320 KB
    float*    vm    = (float*)((char*)d_ws + 335872);     // 8 KB
    uint32_t* gmask = (uint32_t*)((char*)d_ws + 344064);  // 8 KB

    hipLaunchKernelGGL(k_M, dim3(Bc * Hc * Lc / 4), dim3(256), 0, stream, Q, K, M);
    hipLaunchKernelGGL(k_topk, dim3(Bc * Hc), dim3(256), 0, stream, M, top, gmask);
    hipLaunchKernelGGL(k_attn_part, dim3(Bc * Hc * NCH), dim3(256), 0, stream, Q, K, V, top,
                       wsO, wsm, wsl, vpart);
    hipLaunchKernelGGL(k_attn_comb, dim3(Bc * Hc), dim3(256), 0, stream, wsO, wsm, wsl, vpart,
                       stage, vm);
    hipLaunchKernelGGL(k_out, dim3(4096), dim3(256), 0, stream, stage, vm, top, gmask, out);
}